// Round 7
// baseline (68.559 us; speedup 1.0000x reference)
//
#include <hip/hip_runtime.h>
#include <math.h>

static constexpr int S_LEN = 2048;
static constexpr int NROWS = 256 * 2048;           // B*S
static constexpr int TILE  = 64;                   // rows per tile
static constexpr int BLOCK = 256;                  // 4 lanes per row
static constexpr int NBLOCKS = 512;                // exactly 2 per CU (persistent)
static constexpr int TPB   = NROWS / TILE / NBLOCKS;  // 16 tiles per block
static constexpr int BUF_FLOATS = 8192;            // 32 KB per buffer

// per-buffer float offsets (concatenated regions, 64-row tile)
static constexpr int OLG  = 0;      // 64*20 = 1280
static constexpr int OSX  = 1280;
static constexpr int OSY  = 2560;
static constexpr int OSW  = 3840;
static constexpr int OMU  = 5120;   // 64*40 = 2560
static constexpr int OXS  = 7680;   // 64*5  = 320
static constexpr int OPEN = 8000;   // 64*3  = 192 -> ends at 8192 exactly

static constexpr float SIGMA_MIN_F = 0.01f;
static constexpr float LOG_2PI_F   = 1.8378770664093453f;
static constexpr float TMAX_LOG_F  = 9.2103403719761836f;   // log(1e4) >= log(1/(sx*sy))

#define AS1 __attribute__((address_space(1)))
#define AS3 __attribute__((address_space(3)))
__device__ __forceinline__ void gl_lds16(const float* g, float* l) {
    __builtin_amdgcn_global_load_lds((const AS1 void*)g, (AS3 void*)l, 16, 0, 0);
}

// 8 uniform 16B slots per thread: slot = s*256 + t, float off f = slot*4
__device__ __forceinline__ void stage_tile(float* buf, int t, long r0,
    const float* xs, const float* lg, const float* sx, const float* sy,
    const float* sw, const float* mu, const float* pen)
{
    const float* plg = lg  + r0 * 20;
    const float* psx = sx  + r0 * 20;
    const float* psy = sy  + r0 * 20;
    const float* psw = sw  + r0 * 20;
    const float* pmu = mu  + r0 * 40;
    const float* pxs = xs  + r0 * 5;
    const float* ppn = pen + r0 * 3;
    #pragma unroll
    for (int s = 0; s < 8; ++s) {
        const int f = s * 1024 + t * 4;
        const float* src =
            (f < OSX)  ? plg + f :
            (f < OSY)  ? psx + (f - OSX) :
            (f < OSW)  ? psy + (f - OSY) :
            (f < OMU)  ? psw + (f - OSW) :
            (f < OXS)  ? pmu + (f - OMU) :
            (f < OPEN) ? pxs + (f - OXS) :
                         ppn + (f - OPEN);
        gl_lds16(src, buf + f);   // HW: firstlane base + lane*16 == buf + f (consecutive)
    }
}

__global__ __launch_bounds__(BLOCK) void sketch_loss_kernel(
    const float* __restrict__ xs,
    const float* __restrict__ logits,
    const float* __restrict__ mus,
    const float* __restrict__ sxp,
    const float* __restrict__ syp,
    const float* __restrict__ sxyp,
    const float* __restrict__ pen,
    double* __restrict__ acc,          // d_ws: [accP, accE] doubles
    unsigned* __restrict__ counter,    // d_ws byte 16
    float* __restrict__ out)
{
    __shared__ float lds[2 * BUF_FLOATS];
    __shared__ float s_pos[4], s_pen[4];

    const int t = threadIdx.x;
    const int k = t >> 2;            // row within tile (0..63)
    const int h = t & 3;             // quarter: components h, h+4, h+8, h+12, h+16
    const long tile0 = (long)blockIdx.x * TPB;

    float accp = 0.0f, acce = 0.0f;

    // -------- prologue: stage tile 0 and its xn --------
    {
        const long r0 = tile0 * TILE;
        stage_tile(lds, t, r0, xs, logits, sxp, syp, sxyp, mus, pen);
    }
    float xn0, xn1;
    {
        const int r  = (int)(tile0 * TILE) + k;
        const int rn = ((r & (S_LEN - 1)) == S_LEN - 1) ? r - (S_LEN - 1) : r + 1;
        xn0 = xs[rn * 5 + 0];
        xn1 = xs[rn * 5 + 1];
    }

    for (int i = 0; i < TPB; ++i) {
        const float* buf = lds + (i & 1) * BUF_FLOATS;
        float nxn0 = 0.0f, nxn1 = 0.0f;

        __builtin_amdgcn_sched_barrier(0);
        __builtin_amdgcn_s_barrier();            // A: all waves done computing tile i-1
        __builtin_amdgcn_sched_barrier(0);

        if (i + 1 < TPB) {
            const long nr0 = (tile0 + i + 1) * TILE;
            stage_tile(lds + ((i + 1) & 1) * BUF_FLOATS, t, nr0,
                       xs, logits, sxp, syp, sxyp, mus, pen);
            const int nr  = (int)nr0 + k;
            const int nrn = ((nr & (S_LEN - 1)) == S_LEN - 1) ? nr - (S_LEN - 1) : nr + 1;
            nxn0 = xs[nrn * 5 + 0];              // 2 scalar VMEM
            nxn1 = xs[nrn * 5 + 1];
            __builtin_amdgcn_sched_barrier(0);   // pin: exactly 10 VMEM issued above
            asm volatile("s_waitcnt vmcnt(10)" ::: "memory");  // stage(i)+xn(i) complete
        } else {
            __builtin_amdgcn_sched_barrier(0);
            asm volatile("s_waitcnt vmcnt(0)" ::: "memory");
        }
        __builtin_amdgcn_sched_barrier(0);
        __builtin_amdgcn_s_barrier();            // B: buf(cur) fully staged by all waves
        __builtin_amdgcn_sched_barrier(0);

        // -------- compute tile i --------
        const float x0  = buf[OXS + k * 5 + 0];
        const float x1  = buf[OXS + k * 5 + 1];
        const float pt0 = buf[OXS + k * 5 + 2];
        const float pt1 = buf[OXS + k * 5 + 3];
        const float pt2 = buf[OXS + k * 5 + 4];
        const float rel0 = xn0 - x0;
        const float rel1 = xn1 - x1;

        float u[5], tc[5], lvv[5];
        #pragma unroll
        for (int c = 0; c < 5; ++c) {
            const int j = h + 4 * c;             // stride-4 interleave -> 2-way banks (free)
            const float l_  = buf[OLG + k * 20 + j];
            const float sxv = buf[OSX + k * 20 + j];
            const float syv = buf[OSY + k * 20 + j];
            const float swv = buf[OSW + k * 20 + j];
            const float2 m2 = *(const float2*)&buf[OMU + k * 40 + 2 * j];

            const float sx = fmaxf(sxv, SIGMA_MIN_F);
            const float sy = fmaxf(syv, SIGMA_MIN_F);
            const float sw = fminf(fmaxf(swv, -SIGMA_MIN_F), SIGMA_MIN_F);
            const float tt = __builtin_amdgcn_rcpf(sx * sy);
            const float d1 = rel0 - m2.x;
            const float d2 = rel1 - m2.y;
            const float z1 = d1 * sy * tt;
            const float z2 = (d2 - sw * z1) * sx * tt;
            lvv[c] = l_;
            tc[c]  = tt;
            u[c]   = l_ - 0.5f * (z1 * z1 + z2 * z2) - LOG_2PI_F;
        }

        float mu_ = u[0], ml_ = lvv[0];
        #pragma unroll
        for (int c = 1; c < 5; ++c) { mu_ = fmaxf(mu_, u[c]); ml_ = fmaxf(ml_, lvv[c]); }
        mu_ = fmaxf(mu_, __shfl_xor(mu_, 1, 64));
        mu_ = fmaxf(mu_, __shfl_xor(mu_, 2, 64));
        ml_ = fmaxf(ml_, __shfl_xor(ml_, 1, 64));
        ml_ = fmaxf(ml_, __shfl_xor(ml_, 2, 64));
        const float mhat = mu_ + TMAX_LOG_F;

        float s1 = 0.0f, s2 = 0.0f;
        #pragma unroll
        for (int c = 0; c < 5; ++c) {
            s1 += tc[c] * __expf(u[c] - mhat);
            s2 += __expf(lvv[c] - ml_);
        }
        s1 += __shfl_xor(s1, 1, 64);
        s1 += __shfl_xor(s1, 2, 64);
        s2 += __shfl_xor(s2, 1, 64);
        s2 += __shfl_xor(s2, 2, 64);

        const float logp = (mhat + __logf(s1)) - (ml_ + __logf(s2));

        const float q0 = buf[OPEN + k * 3 + 0];
        const float q1 = buf[OPEN + k * 3 + 1];
        const float q2 = buf[OPEN + k * 3 + 2];
        const float mq = fmaxf(fmaxf(q0, q1), q2);
        const float lseq = mq + __logf(__expf(q0 - mq) + __expf(q1 - mq) + __expf(q2 - mq));
        const float penv = pt0 * (q0 - lseq) + pt1 * (q1 - lseq) + pt2 * (q2 - lseq);

        accp += logp * 0.25f;
        acce += penv * 0.25f;
        xn0 = nxn0;
        xn1 = nxn1;
    }

    // -------- block reduction (fixed tree: deterministic per block) --------
    const int lane = t & 63;
    const int wid  = t >> 6;
    #pragma unroll
    for (int off = 32; off > 0; off >>= 1) {
        accp += __shfl_down(accp, off, 64);
        acce += __shfl_down(acce, off, 64);
    }
    if (lane == 0) { s_pos[wid] = accp; s_pen[wid] = acce; }
    __syncthreads();

    // -------- fused finalize: f64 atomics + ticket counter --------
    if (t == 0) {
        const double bp = (double)s_pos[0] + (double)s_pos[1] + (double)s_pos[2] + (double)s_pos[3];
        const double be = (double)s_pen[0] + (double)s_pen[1] + (double)s_pen[2] + (double)s_pen[3];
        atomicAdd(&acc[0], bp);
        atomicAdd(&acc[1], be);
        __threadfence();                          // release: partial sums visible device-wide
        const unsigned old = atomicAdd(counter, 1u);
        if (old == (unsigned)(NBLOCKS - 1)) {     // last block finalizes
            __threadfence();                      // acquire
            const double P = __hip_atomic_load(&acc[0], __ATOMIC_RELAXED, __HIP_MEMORY_SCOPE_AGENT);
            const double E = __hip_atomic_load(&acc[1], __ATOMIC_RELAXED, __HIP_MEMORY_SCOPE_AGENT);
            out[0] = (float)(-P / (double)NROWS);
            out[1] = (float)(-E / (double)NROWS);
        }
    }
}

extern "C" void kernel_launch(void* const* d_in, const int* in_sizes, int n_in,
                              void* d_out, int out_size, void* d_ws, size_t ws_size,
                              hipStream_t stream) {
    const float* xs     = (const float*)d_in[0];
    const float* logits = (const float*)d_in[1];
    const float* mus    = (const float*)d_in[2];
    const float* sx     = (const float*)d_in[3];
    const float* sy     = (const float*)d_in[4];
    const float* sxy    = (const float*)d_in[5];
    const float* pen    = (const float*)d_in[6];
    float* out = (float*)d_out;

    double*   acc     = (double*)d_ws;                 // [0..15]: accP, accE
    unsigned* counter = (unsigned*)((char*)d_ws + 16); // [16..19]

    // zero accumulators + ticket counter every call (graph-capturable)
    hipMemsetAsync(d_ws, 0, 32, stream);

    sketch_loss_kernel<<<NBLOCKS, BLOCK, 0, stream>>>(
        xs, logits, mus, sx, sy, sxy, pen, acc, counter, out);
}

// Round 8
// 47.549 us; speedup vs baseline: 1.4418x; 1.4418x over previous
//
#include <hip/hip_runtime.h>
#include <math.h>

static constexpr int S_LEN = 2048;
static constexpr int NROWS = 256 * 2048;           // B*S
static constexpr int TILE  = 64;                   // rows per tile
static constexpr int BLOCK = 256;                  // 4 lanes per row
static constexpr int NBLOCKS = 512;                // exactly 2 per CU (persistent)
static constexpr int TPB   = NROWS / TILE / NBLOCKS;  // 16 tiles per block
static constexpr int BUF_FLOATS = 8192;            // 32 KB per buffer

// per-buffer float offsets (concatenated regions, 64-row tile)
static constexpr int OLG  = 0;      // 64*20 = 1280
static constexpr int OSX  = 1280;
static constexpr int OSY  = 2560;
static constexpr int OSW  = 3840;
static constexpr int OMU  = 5120;   // 64*40 = 2560
static constexpr int OXS  = 7680;   // 64*5  = 320
static constexpr int OPEN = 8000;   // 64*3  = 192 -> ends at 8192 exactly

static constexpr float SIGMA_MIN_F = 0.01f;
static constexpr float LOG_2PI_F   = 1.8378770664093453f;
static constexpr float TMAX_LOG_F  = 9.2103403719761836f;   // log(1e4) >= log(1/(sx*sy))

#define AS1 __attribute__((address_space(1)))
#define AS3 __attribute__((address_space(3)))
__device__ __forceinline__ void gl_lds16(const float* g, float* l) {
    __builtin_amdgcn_global_load_lds((const AS1 void*)g, (AS3 void*)l, 16, 0, 0);
}

// 8 uniform 16B slots per thread: slot = s*256 + t, float off f = slot*4
__device__ __forceinline__ void stage_tile(float* buf, int t, long r0,
    const float* xs, const float* lg, const float* sx, const float* sy,
    const float* sw, const float* mu, const float* pen)
{
    const float* plg = lg  + r0 * 20;
    const float* psx = sx  + r0 * 20;
    const float* psy = sy  + r0 * 20;
    const float* psw = sw  + r0 * 20;
    const float* pmu = mu  + r0 * 40;
    const float* pxs = xs  + r0 * 5;
    const float* ppn = pen + r0 * 3;
    #pragma unroll
    for (int s = 0; s < 8; ++s) {
        const int f = s * 1024 + t * 4;
        const float* src =
            (f < OSX)  ? plg + f :
            (f < OSY)  ? psx + (f - OSX) :
            (f < OSW)  ? psy + (f - OSY) :
            (f < OMU)  ? psw + (f - OSW) :
            (f < OXS)  ? pmu + (f - OMU) :
            (f < OPEN) ? pxs + (f - OXS) :
                         ppn + (f - OPEN);
        gl_lds16(src, buf + f);   // HW: firstlane base + lane*16 == buf + f (consecutive)
    }
}

__global__ __launch_bounds__(BLOCK) void sketch_loss_kernel(
    const float* __restrict__ xs,
    const float* __restrict__ logits,
    const float* __restrict__ mus,
    const float* __restrict__ sxp,
    const float* __restrict__ syp,
    const float* __restrict__ sxyp,
    const float* __restrict__ pen,
    float* __restrict__ partials)
{
    __shared__ float lds[2 * BUF_FLOATS];
    __shared__ float s_pos[4], s_pen[4];

    const int t = threadIdx.x;
    const int k = t >> 2;            // row within tile (0..63)
    const int h = t & 3;             // quarter: components h, h+4, h+8, h+12, h+16
    const long tile0 = (long)blockIdx.x * TPB;

    float accp = 0.0f, acce = 0.0f;

    // -------- prologue: stage tile 0 and its xn --------
    {
        const long r0 = tile0 * TILE;
        stage_tile(lds, t, r0, xs, logits, sxp, syp, sxyp, mus, pen);
    }
    float xn0, xn1;
    {
        const int r  = (int)(tile0 * TILE) + k;
        const int rn = ((r & (S_LEN - 1)) == S_LEN - 1) ? r - (S_LEN - 1) : r + 1;
        xn0 = xs[rn * 5 + 0];
        xn1 = xs[rn * 5 + 1];
    }

    for (int i = 0; i < TPB; ++i) {
        const float* buf = lds + (i & 1) * BUF_FLOATS;
        float nxn0 = 0.0f, nxn1 = 0.0f;

        __builtin_amdgcn_sched_barrier(0);
        __builtin_amdgcn_s_barrier();            // A: all waves done computing tile i-1
        __builtin_amdgcn_sched_barrier(0);

        if (i + 1 < TPB) {
            const long nr0 = (tile0 + i + 1) * TILE;
            stage_tile(lds + ((i + 1) & 1) * BUF_FLOATS, t, nr0,
                       xs, logits, sxp, syp, sxyp, mus, pen);
            const int nr  = (int)nr0 + k;
            const int nrn = ((nr & (S_LEN - 1)) == S_LEN - 1) ? nr - (S_LEN - 1) : nr + 1;
            nxn0 = xs[nrn * 5 + 0];              // 2 scalar VMEM (20B stride, 8B-align unsafe)
            nxn1 = xs[nrn * 5 + 1];
            __builtin_amdgcn_sched_barrier(0);   // pin: exactly 10 VMEM issued above
            asm volatile("s_waitcnt vmcnt(10)" ::: "memory");  // stage(i)+xn(i) complete
        } else {
            __builtin_amdgcn_sched_barrier(0);
            asm volatile("s_waitcnt vmcnt(0)" ::: "memory");
        }
        __builtin_amdgcn_sched_barrier(0);
        __builtin_amdgcn_s_barrier();            // B: buf(cur) fully staged by all waves
        __builtin_amdgcn_sched_barrier(0);

        // -------- compute tile i --------
        const float x0  = buf[OXS + k * 5 + 0];
        const float x1  = buf[OXS + k * 5 + 1];
        const float pt0 = buf[OXS + k * 5 + 2];
        const float pt1 = buf[OXS + k * 5 + 3];
        const float pt2 = buf[OXS + k * 5 + 4];
        const float rel0 = xn0 - x0;
        const float rel1 = xn1 - x1;

        float u[5], tc[5], lvv[5];
        #pragma unroll
        for (int c = 0; c < 5; ++c) {
            const int j = h + 4 * c;             // stride-4 interleave -> 2-way banks (free)
            const float l_  = buf[OLG + k * 20 + j];
            const float sxv = buf[OSX + k * 20 + j];
            const float syv = buf[OSY + k * 20 + j];
            const float swv = buf[OSW + k * 20 + j];
            const float2 m2 = *(const float2*)&buf[OMU + k * 40 + 2 * j];

            const float sx = fmaxf(sxv, SIGMA_MIN_F);
            const float sy = fmaxf(syv, SIGMA_MIN_F);
            const float sw = fminf(fmaxf(swv, -SIGMA_MIN_F), SIGMA_MIN_F);
            const float tt = __builtin_amdgcn_rcpf(sx * sy);
            const float d1 = rel0 - m2.x;
            const float d2 = rel1 - m2.y;
            const float z1 = d1 * sy * tt;
            const float z2 = (d2 - sw * z1) * sx * tt;
            lvv[c] = l_;
            tc[c]  = tt;
            u[c]   = l_ - 0.5f * (z1 * z1 + z2 * z2) - LOG_2PI_F;
        }

        float mu_ = u[0], ml_ = lvv[0];
        #pragma unroll
        for (int c = 1; c < 5; ++c) { mu_ = fmaxf(mu_, u[c]); ml_ = fmaxf(ml_, lvv[c]); }
        mu_ = fmaxf(mu_, __shfl_xor(mu_, 1, 64));
        mu_ = fmaxf(mu_, __shfl_xor(mu_, 2, 64));
        ml_ = fmaxf(ml_, __shfl_xor(ml_, 1, 64));
        ml_ = fmaxf(ml_, __shfl_xor(ml_, 2, 64));
        const float mhat = mu_ + TMAX_LOG_F;

        float s1 = 0.0f, s2 = 0.0f;
        #pragma unroll
        for (int c = 0; c < 5; ++c) {
            s1 += tc[c] * __expf(u[c] - mhat);
            s2 += __expf(lvv[c] - ml_);
        }
        s1 += __shfl_xor(s1, 1, 64);
        s1 += __shfl_xor(s1, 2, 64);
        s2 += __shfl_xor(s2, 1, 64);
        s2 += __shfl_xor(s2, 2, 64);

        const float logp = (mhat + __logf(s1)) - (ml_ + __logf(s2));

        const float q0 = buf[OPEN + k * 3 + 0];
        const float q1 = buf[OPEN + k * 3 + 1];
        const float q2 = buf[OPEN + k * 3 + 2];
        const float mq = fmaxf(fmaxf(q0, q1), q2);
        const float lseq = mq + __logf(__expf(q0 - mq) + __expf(q1 - mq) + __expf(q2 - mq));
        const float penv = pt0 * (q0 - lseq) + pt1 * (q1 - lseq) + pt2 * (q2 - lseq);

        accp += logp * 0.25f;
        acce += penv * 0.25f;
        xn0 = nxn0;
        xn1 = nxn1;
    }

    // -------- block reduction --------
    const int lane = t & 63;
    const int wid  = t >> 6;
    #pragma unroll
    for (int off = 32; off > 0; off >>= 1) {
        accp += __shfl_down(accp, off, 64);
        acce += __shfl_down(acce, off, 64);
    }
    if (lane == 0) { s_pos[wid] = accp; s_pen[wid] = acce; }
    __syncthreads();
    if (t == 0) {
        partials[blockIdx.x * 2 + 0] = s_pos[0] + s_pos[1] + s_pos[2] + s_pos[3];
        partials[blockIdx.x * 2 + 1] = s_pen[0] + s_pen[1] + s_pen[2] + s_pen[3];
    }
}

__global__ __launch_bounds__(256) void sketch_reduce_kernel(
    const float* __restrict__ partials, float* __restrict__ out)
{
    float tp = 0.0f, te = 0.0f;
    for (int i = threadIdx.x; i < NBLOCKS; i += 256) {
        tp += partials[2 * i + 0];
        te += partials[2 * i + 1];
    }
    #pragma unroll
    for (int off = 32; off > 0; off >>= 1) {
        tp += __shfl_down(tp, off, 64);
        te += __shfl_down(te, off, 64);
    }
    __shared__ float sp[4], se[4];
    const int lane = threadIdx.x & 63;
    const int wid  = threadIdx.x >> 6;
    if (lane == 0) { sp[wid] = tp; se[wid] = te; }
    __syncthreads();
    if (threadIdx.x == 0) {
        const float P = sp[0] + sp[1] + sp[2] + sp[3];
        const float E = se[0] + se[1] + se[2] + se[3];
        out[0] = -P / (float)NROWS;
        out[1] = -E / (float)NROWS;
    }
}

extern "C" void kernel_launch(void* const* d_in, const int* in_sizes, int n_in,
                              void* d_out, int out_size, void* d_ws, size_t ws_size,
                              hipStream_t stream) {
    const float* xs     = (const float*)d_in[0];
    const float* logits = (const float*)d_in[1];
    const float* mus    = (const float*)d_in[2];
    const float* sx     = (const float*)d_in[3];
    const float* sy     = (const float*)d_in[4];
    const float* sxy    = (const float*)d_in[5];
    const float* pen    = (const float*)d_in[6];
    float* out = (float*)d_out;
    float* partials = (float*)d_ws;              // NBLOCKS*2 floats = 4 KiB

    sketch_loss_kernel<<<NBLOCKS, BLOCK, 0, stream>>>(xs, logits, mus, sx, sy, sxy, pen, partials);
    sketch_reduce_kernel<<<1, 256, 0, stream>>>(partials, out);
}